// Round 4
// baseline (4139.980 us; speedup 1.0000x reference)
//
#include <hip/hip_runtime.h>

// GRU + linear readout, B=128 T=2048 IN=32 H=256 L=16.
// One block per batch row (128 blocks), 256 threads = 4 waves, ONE block/CU.
// Full 512-VGPR/wave budget pinned via amdgpu_waves_per_eu(1,1).
// Whh (f16) ENTIRELY register-resident: 12 n-tiles x 8 k-tiles = 384 VGPR/lane.
// Wih (f16) in LDS (contiguous per-tile fragments). One barrier per step,
// double-buffered h in LDS. Gates computed wave-locally from MFMA accumulators
// (batch dim padded 1->16, all A rows broadcast-identical).

typedef _Float16 half8 __attribute__((ext_vector_type(8)));
typedef float float4v __attribute__((ext_vector_type(4)));

#define TT 2048
#define LOG2E 1.44269504088896f

__device__ __forceinline__ float sigm(float x) {
    return __builtin_amdgcn_rcpf(1.f + __builtin_amdgcn_exp2f(-LOG2E * x));
}
__device__ __forceinline__ float tanhf_(float x) {
    float e = __builtin_amdgcn_exp2f(2.f * LOG2E * x);   // inf-safe: ->1 / ->-1
    return 1.f - 2.f * __builtin_amdgcn_rcpf(e + 1.f);
}

__attribute__((amdgpu_flat_work_group_size(256, 256), amdgpu_waves_per_eu(1, 1)))
__global__ void gru_kernel(const float* __restrict__ xg,    // [B,T,32]
                           const float* __restrict__ xlin,  // [B,T,16]
                           const float* __restrict__ h0,    // [B,256]
                           const float* __restrict__ Wih,   // [768,32]
                           const float* __restrict__ Whh,   // [768,256]
                           const float* __restrict__ bias,  // [768]
                           const float* __restrict__ biasn, // [256]
                           float* __restrict__ out)         // [B*T]
{
    __shared__ _Float16 ldsWx[24576];    // 48 KB: Wih f16, chunk = [gtile][lhi][l15][8]
    __shared__ _Float16 ldsH[2][256];    // double-buffered hidden state

    const int tid  = threadIdx.x;
    const int b    = blockIdx.x;
    const int lane = tid & 63;
    const int w    = tid >> 6;      // wave 0..3
    const int l15  = lane & 15;
    const int lhi  = lane >> 4;     // 0..3 (k-chunk)

    // ---- Whh -> registers (f16 RTN): wave w owns tiles g*16 + w*4 + q
    half8 Wh[12][8];
#pragma unroll
    for (int nt = 0; nt < 12; ++nt) {
        const int gtile = (nt >> 2) * 16 + w * 4 + (nt & 3);
        const int row = gtile * 16 + l15;
#pragma unroll
        for (int kt = 0; kt < 8; ++kt) {
            const float4v* pp = (const float4v*)(Whh + row * 256 + kt * 32 + lhi * 8);
            float4v u = pp[0], v2 = pp[1];
            half8 hv;
#pragma unroll
            for (int j = 0; j < 4; ++j) { hv[j] = (_Float16)u[j]; hv[4 + j] = (_Float16)v2[j]; }
            Wh[nt][kt] = hv;
        }
    }

    // ---- Wih -> LDS f16; dest so each tile's wave-read is 1024B contiguous
    for (int c = tid; c < 3072; c += 256) {        // 768 rows * 4 k-chunks
        const int row = c >> 2, qc = c & 3;
        const float* p = Wih + row * 32 + qc * 8;
        half8 v;
#pragma unroll
        for (int j = 0; j < 8; ++j) v[j] = (_Float16)p[j];
        *(half8*)((char*)ldsWx + (((row >> 4) * 64) + qc * 16 + (row & 15)) * 16) = v;
    }

    // ---- biases + hidden state for this wave's 4 column groups
    float br[4], bz[4], bi[4], bn4[4], hreg[4];
#pragma unroll
    for (int q = 0; q < 4; ++q) {
        const int c = w * 64 + q * 16 + l15;
        br[q]  = bias[c];
        bz[q]  = bias[256 + c];
        bi[q]  = bias[512 + c];
        bn4[q] = biasn[c];
        hreg[q] = h0[b * 256 + c];
    }
    ldsH[0][tid] = (_Float16)h0[b * 256 + tid];

    // ---- x_0 fragment into registers
    const float* xgb = xg + (size_t)b * TT * 32;
    half8 ax;
    {
        const float4v* px = (const float4v*)(xgb + lhi * 8);
        float4v u = px[0], v2 = px[1];
#pragma unroll
        for (int j = 0; j < 4; ++j) { ax[j] = (_Float16)u[j]; ax[4 + j] = (_Float16)v2[j]; }
    }
    float xlc = 0.f;
    if (w == 0 && lane < 16) xlc = xlin[(size_t)b * TT * 16 + lane];

    __syncthreads();

    const float4v zero4 = {0.f, 0.f, 0.f, 0.f};

#pragma clang loop unroll(disable)
    for (int t = 0; t < TT; ++t) {
        const int p  = t & 1;
        const int tn = (t < TT - 1) ? t + 1 : t;

        // prefetch next-step inputs (latency hidden under MFMAs)
        const float4v* px = (const float4v*)(xgb + (size_t)tn * 32 + lhi * 8);
        float4v xa = px[0], xb2 = px[1];
        float xln = 0.f;
        if (w == 0 && lane < 16) xln = xlin[((size_t)b * TT + tn) * 16 + lane];

        // ---- x-side MFMAs (K=32=IN): seed r/z accs; n-gate x-part kept separate
        float4v acc[12];
        float xn4[4];
#pragma unroll
        for (int nt = 0; nt < 12; ++nt) {
            const int gtile = (nt >> 2) * 16 + w * 4 + (nt & 3);
            half8 wx = *(const half8*)((const char*)ldsWx + gtile * 1024 + lhi * 256 + l15 * 16);
            float4v xq = __builtin_amdgcn_mfma_f32_16x16x32_f16(ax, wx, zero4, 0, 0, 0);
            if (nt >= 8) { xn4[nt - 8] = xq[0]; acc[nt] = zero4; }
            else         { acc[nt] = xq; }
        }
        // ---- h-side MFMAs over 8 k-tiles, weights all in registers
#pragma unroll
        for (int kt = 0; kt < 8; ++kt) {
            half8 a = ((const half8*)ldsH[p])[kt * 4 + lhi];   // broadcast h fragment
#pragma unroll
            for (int nt = 0; nt < 12; ++nt)
                acc[nt] = __builtin_amdgcn_mfma_f32_16x16x32_f16(a, Wh[nt][kt], acc[nt], 0, 0, 0);
        }

        // ---- gates: wave-local, straight from accumulators (row 0 on all lanes)
#pragma unroll
        for (int q = 0; q < 4; ++q) {
            float r = sigm(acc[q][0] + br[q]);
            float z = sigm(acc[4 + q][0] + bz[q]);
            float n = tanhf_(xn4[q] + bi[q] + r * (acc[8 + q][0] + bn4[q]));
            float hnew = n + z * (hreg[q] - n);
            hreg[q] = hnew;
            if (lane < 16) ldsH[p ^ 1][w * 64 + q * 16 + l15] = (_Float16)hnew;
        }

        // ---- readout: cols 0..15 live in wave 0 group q=0
        if (w == 0) {
            float v = hreg[0] * xlc;
            v += __shfl_xor(v, 8, 16);
            v += __shfl_xor(v, 4, 16);
            v += __shfl_xor(v, 2, 16);
            v += __shfl_xor(v, 1, 16);
            if (lane == 0) out[(size_t)b * TT + t] = v;
        }

        // ---- commit prefetched x for next step
#pragma unroll
        for (int j = 0; j < 4; ++j) { ax[j] = (_Float16)xa[j]; ax[4 + j] = (_Float16)xb2[j]; }
        xlc = xln;
        __syncthreads();   // new h visible; old buffer free
    }
}

extern "C" void kernel_launch(void* const* d_in, const int* in_sizes, int n_in,
                              void* d_out, int out_size, void* d_ws, size_t ws_size,
                              hipStream_t stream) {
    const float* xg    = (const float*)d_in[0];
    const float* xlin  = (const float*)d_in[1];
    const float* h0    = (const float*)d_in[2];
    const float* Wih   = (const float*)d_in[3];
    const float* Whh   = (const float*)d_in[4];
    const float* bias  = (const float*)d_in[5];
    const float* biasn = (const float*)d_in[6];
    float* out = (float*)d_out;

    gru_kernel<<<128, 256, 0, stream>>>(xg, xlin, h0, Wih, Whh, bias, biasn, out);
}

// Round 5
// 2512.450 us; speedup vs baseline: 1.6478x; 1.6478x over previous
//
#include <hip/hip_runtime.h>

// GRU + linear readout, B=128 T=2048 IN=32 H=256 L=16.
// One block per batch row (128 blocks), 512 threads = 8 waves, pinned to
// 2 waves/EU -> 256-VGPR/wave budget. Whh (f16) k-tiles 0..6 register-
// resident (168 VGPR/lane); k-tile 7 + Wih in LDS (chunk-major, conflict-
// free). Wave w owns gate-matched tiles {2w,2w+1,2w+16,2w+17,2w+32,2w+33}
// so gate math is wave-local from MFMA accumulators; ONE barrier/step;
// double-buffered h (2x256 f16) in LDS; x_t fragment prefetched in regs.

typedef _Float16 half8 __attribute__((ext_vector_type(8)));
typedef float float4v __attribute__((ext_vector_type(4)));

#define TT 2048
#define LOG2E 1.44269504088896f

__device__ __forceinline__ float sigm(float x) {
    return __builtin_amdgcn_rcpf(1.f + __builtin_amdgcn_exp2f(-LOG2E * x));
}
__device__ __forceinline__ float tanhf_(float x) {
    float e = __builtin_amdgcn_exp2f(2.f * LOG2E * x);   // inf-safe: ->1 / ->-1
    return 1.f - 2.f * __builtin_amdgcn_rcpf(e + 1.f);
}

__attribute__((amdgpu_flat_work_group_size(512, 512), amdgpu_waves_per_eu(2, 2)))
__global__ void gru_kernel(const float* __restrict__ xg,    // [B,T,32]
                           const float* __restrict__ xlin,  // [B,T,16]
                           const float* __restrict__ h0,    // [B,256]
                           const float* __restrict__ Wih,   // [768,32]
                           const float* __restrict__ Whh,   // [768,256]
                           const float* __restrict__ bias,  // [768]
                           const float* __restrict__ biasn, // [256]
                           float* __restrict__ out)         // [B*T]
{
    __shared__ _Float16 ldsW[24576];     // 48 KB: Whh k-tile 7 (k=224..255),
                                         // chunk-major: byte = qc*12288 + row*16
    __shared__ _Float16 ldsWx[24576];    // 48 KB: Wih, [gtile][lhi][l15] 16B chunks
    __shared__ _Float16 ldsH[2][256];    // double-buffered hidden state

    const int tid  = threadIdx.x;
    const int b    = blockIdx.x;
    const int lane = tid & 63;
    const int w    = tid >> 6;      // wave 0..7
    const int l15  = lane & 15;
    const int lhi  = lane >> 4;     // 0..3 (k-chunk)

    // ---- Whh k-tiles 0..6 -> registers (f16 RTN)
    half8 Wh[6][7];
#pragma unroll
    for (int nt = 0; nt < 6; ++nt) {
        const int gtile = 2 * w + (nt >> 1) * 16 + (nt & 1);
        const int row = gtile * 16 + l15;
#pragma unroll
        for (int kt = 0; kt < 7; ++kt) {
            const float4v* pp = (const float4v*)(Whh + row * 256 + kt * 32 + lhi * 8);
            float4v u = pp[0], v2 = pp[1];
            half8 hv;
#pragma unroll
            for (int j = 0; j < 4; ++j) { hv[j] = (_Float16)u[j]; hv[4 + j] = (_Float16)v2[j]; }
            Wh[nt][kt] = hv;
        }
    }

    // ---- Whh k-tile 7 -> LDS, chunk-major, every byte written exactly once
    for (int c = tid; c < 3072; c += 512) {        // 768 rows * 4 chunks
        const int n = c >> 2, qc = c & 3;
        const float* p = Whh + n * 256 + 224 + qc * 8;
        half8 v;
#pragma unroll
        for (int j = 0; j < 8; ++j) v[j] = (_Float16)p[j];
        *(half8*)((char*)ldsW + qc * 12288 + n * 16) = v;
    }
    // ---- Wih -> LDS; per-tile fragment read is 1024B contiguous
    for (int c = tid; c < 3072; c += 512) {        // 768 rows * 4 k-chunks
        const int row = c >> 2, qc = c & 3;
        const float* p = Wih + row * 32 + qc * 8;
        half8 v;
#pragma unroll
        for (int j = 0; j < 8; ++j) v[j] = (_Float16)p[j];
        *(half8*)((char*)ldsWx + (((row >> 4) * 64) + qc * 16 + (row & 15)) * 16) = v;
    }

    // ---- biases + hidden state for this wave's 2 column groups
    float br[2], bz[2], bi[2], bn2[2], hreg[2];
#pragma unroll
    for (int q = 0; q < 2; ++q) {
        const int c = w * 32 + q * 16 + l15;
        br[q]  = bias[c];
        bz[q]  = bias[256 + c];
        bi[q]  = bias[512 + c];
        bn2[q] = biasn[c];
        hreg[q] = h0[b * 256 + c];
    }
    if (tid < 256) ldsH[0][tid] = (_Float16)h0[b * 256 + tid];

    // ---- x_0 fragment into registers
    const float* xgb = xg + (size_t)b * TT * 32;
    half8 ax;
    {
        const float4v* px = (const float4v*)(xgb + lhi * 8);
        float4v u = px[0], v2 = px[1];
#pragma unroll
        for (int j = 0; j < 4; ++j) { ax[j] = (_Float16)u[j]; ax[4 + j] = (_Float16)v2[j]; }
    }
    float xlc = 0.f;
    if (w == 0 && lane < 16) xlc = xlin[(size_t)b * TT * 16 + lane];

    __syncthreads();

    const int wb = lhi * 12288 + l15 * 16 + w * 512;   // kt7 LDS base (+512B per tile pair)
    const float4v zero4 = {0.f, 0.f, 0.f, 0.f};

#pragma clang loop unroll(disable)
    for (int t = 0; t < TT; ++t) {
        const int p  = t & 1;
        const int tn = (t < TT - 1) ? t + 1 : t;

        // prefetch next-step inputs (latency hidden under MFMAs)
        const float4v* px = (const float4v*)(xgb + (size_t)tn * 32 + lhi * 8);
        float4v xa = px[0], xb2 = px[1];
        float xln = 0.f;
        if (w == 0 && lane < 16) xln = xlin[((size_t)b * TT + tn) * 16 + lane];

        // ---- x-side MFMAs (K=32=IN): seed r/z accs; n-gate x-part separate
        float4v acc[6];
        float xn2[2];
#pragma unroll
        for (int nt = 0; nt < 6; ++nt) {
            const int gtile = 2 * w + (nt >> 1) * 16 + (nt & 1);
            half8 wx = *(const half8*)((const char*)ldsWx + gtile * 1024 + lhi * 256 + l15 * 16);
            float4v xq = __builtin_amdgcn_mfma_f32_16x16x32_f16(ax, wx, zero4, 0, 0, 0);
            if (nt >= 4) { xn2[nt - 4] = xq[0]; acc[nt] = zero4; }
            else         { acc[nt] = xq; }
        }
        // ---- h-side MFMAs over 8 k-tiles (kt 0..6 regs, kt 7 LDS)
#pragma unroll
        for (int kt = 0; kt < 8; ++kt) {
            half8 a = ((const half8*)ldsH[p])[kt * 4 + lhi];   // broadcast h fragment
#pragma unroll
            for (int nt = 0; nt < 6; ++nt) {
                half8 bb;
                if (kt < 7) bb = Wh[nt][kt];
                else        bb = *(const half8*)((const char*)ldsW + wb
                                      + (nt >> 1) * 4096 + (nt & 1) * 256);
                acc[nt] = __builtin_amdgcn_mfma_f32_16x16x32_f16(a, bb, acc[nt], 0, 0, 0);
            }
        }

        // ---- gates: wave-local, straight from accumulators (row 0 on all lanes)
#pragma unroll
        for (int q = 0; q < 2; ++q) {
            float r = sigm(acc[q][0] + br[q]);
            float z = sigm(acc[2 + q][0] + bz[q]);
            float n = tanhf_(xn2[q] + bi[q] + r * (acc[4 + q][0] + bn2[q]));
            float hnew = n + z * (hreg[q] - n);
            hreg[q] = hnew;
            if (lane < 16) ldsH[p ^ 1][w * 32 + q * 16 + l15] = (_Float16)hnew;
        }

        // ---- readout: cols 0..15 live in wave 0, group q=0
        if (w == 0) {
            float v = hreg[0] * xlc;
            v += __shfl_xor(v, 8, 16);
            v += __shfl_xor(v, 4, 16);
            v += __shfl_xor(v, 2, 16);
            v += __shfl_xor(v, 1, 16);
            if (lane == 0) out[(size_t)b * TT + t] = v;
        }

        // ---- commit prefetched x for next step
#pragma unroll
        for (int j = 0; j < 4; ++j) { ax[j] = (_Float16)xa[j]; ax[4 + j] = (_Float16)xb2[j]; }
        xlc = xln;
        __syncthreads();   // new h visible; old buffer free
    }
}

extern "C" void kernel_launch(void* const* d_in, const int* in_sizes, int n_in,
                              void* d_out, int out_size, void* d_ws, size_t ws_size,
                              hipStream_t stream) {
    const float* xg    = (const float*)d_in[0];
    const float* xlin  = (const float*)d_in[1];
    const float* h0    = (const float*)d_in[2];
    const float* Wih   = (const float*)d_in[3];
    const float* Whh   = (const float*)d_in[4];
    const float* bias  = (const float*)d_in[5];
    const float* biasn = (const float*)d_in[6];
    float* out = (float*)d_out;

    gru_kernel<<<128, 512, 0, stream>>>(xg, xlin, h0, Wih, Whh, bias, biasn, out);
}